// Round 7
// baseline (4195.394 us; speedup 1.0000x reference)
//
#include <hip/hip_runtime.h>
#include <math.h>

// ---------------- workspace layout (float offsets) ----------------
#define OFF_CWS  0L         // conv w  [l8][wv16][s576][o16]     = 1179648
#define OFF_FWS  1179648L   // fus  w  [l8][wv16][i128][o16]     = 262144
#define OFF_W1G  1441792L   // W1G  [c256][o512]                 = 131072
#define OFF_W1H  1572864L   // W1H  [wv16][i1024][o32]           = 524288
#define OFF_W2S  2097152L   // W2S  [c4][wv16][i128][o4]         = 32768
#define OFF_GRAW 2129920L   // graw [512][256]                   = 131072
#define OFF_HG   2260992L   // hg   [512][512]                   = 262144
#define OFF_DYN  2523136L   // dynamic: states [C][1024][128]
#define REPACK_N 2129920L

__global__ void k_repack(const float* __restrict__ head_w, const float* __restrict__ res_w,
                         const float* __restrict__ fusion_w,
                         const float* __restrict__ pred1_w, const float* __restrict__ cls1_w,
                         const float* __restrict__ pred2_w, const float* __restrict__ cls2_w,
                         float* __restrict__ ws) {
  long j = (long)blockIdx.x * 256 + threadIdx.x;
  if (j >= REPACK_N) return;
  if (j < OFF_FWS) {                       // CWS[l][wv][s][o16], split-k layout
    int o = (int)(j & 15); long q = j >> 4;
    int s = (int)(q % 576); long q2 = q / 576;
    int wv = (int)(q2 & 15), l = (int)(q2 >> 4);
    int og = (wv & 7) * 16 + o;
    int k, i;
    if (wv < 8) { k = (s < 512) ? (s >> 7) : 8;     i = (s < 512) ? (s & 127) : (s - 512); }
    else        { k = (s < 512) ? 4 + (s >> 7) : 8; i = (s < 512) ? (s & 127) : 64 + (s - 512); }
    float v;
    if (l == 0) v = (i < 67) ? head_w[(og * 67 + i) * 9 + k] : 0.f;
    else        v = res_w[(((l - 1) * 128 + og) * 128 + i) * 9 + k];
    ws[j] = v;
  } else if (j < OFF_W1G) {                // FWS[l][wv][i][o16]
    long q = j - OFF_FWS;
    int o = (int)(q & 15), i = (int)((q >> 4) & 127), wv = (int)((q >> 11) & 15), l = (int)(q >> 15);
    ws[j] = fusion_w[(long)(wv * 16 + o) * 1024 + l * 128 + i];
  } else if (j < OFF_W1H) {                // W1G[c][o]
    long q = j - OFF_W1G; int o = (int)(q & 511); int c = (int)(q >> 9);
    ws[j] = (o < 256) ? pred1_w[(long)o * 1280 + c] : cls1_w[(long)(o - 256) * 1280 + c];
  } else if (j < OFF_W2S) {                // W1H[wv][i][o32]
    long q = j - OFF_W1H;
    int o = (int)(q & 31), i = (int)((q >> 5) & 1023), wv = (int)(q >> 15);
    int ho = wv * 32 + o, c = 256 + i;
    ws[j] = (ho < 256) ? pred1_w[(long)ho * 1280 + c] : cls1_w[(long)(ho - 256) * 1280 + c];
  } else if (j < OFF_GRAW) {               // W2S[c][wv][i][o4]
    long q = j - OFF_W2S;
    int o = (int)(q & 3), i = (int)((q >> 2) & 127), wv = (int)((q >> 9) & 15), c = (int)(q >> 13);
    int jg = wv * 4 + o;
    ws[j] = (c < 2) ? pred2_w[jg * 256 + c * 128 + i] : cls2_w[jg * 256 + (c - 2) * 128 + i];
  }
}

// =============== K1: gather + 8-layer conv (split-k) + incremental fus + states ===============
__global__ __launch_bounds__(1024) __attribute__((amdgpu_waves_per_eu(4)))
void k_conv(const float* __restrict__ cnn, const float* __restrict__ i_it,
            const float* __restrict__ c_it, const float* __restrict__ cls_in,
            const int* __restrict__ ind,
            const float* __restrict__ CWS, const float* __restrict__ FWS,
            const float* __restrict__ head_b, const float* __restrict__ res_b,
            float* __restrict__ graw, float* __restrict__ states, int p0) {
  __shared__ float sx[16384];    // [128 ch][128 pos] 64 KB
  __shared__ float part[16384];  // split-k partial sums 64 KB
  const int ln = blockIdx.x, n = p0 + ln, t = threadIdx.x;
  const int po = t & 63;
  const int wv = __builtin_amdgcn_readfirstlane(t >> 6);
  const int gA = (wv < 8);
  const int ow = (wv & 7) * 16;     // this wave's 16 conv out-channels

  // ---- bilinear gather ----
  {
    const int p4 = t & 127, og4 = t >> 7;
    const float gx = i_it[((long)n * 128 + p4) * 2 + 0] - 0.5f;
    const float gy = i_it[((long)n * 128 + p4) * 2 + 1] - 0.5f;
    const float fx = floorf(gx), fy = floorf(gy);
    const float wx = gx - fx, wy = gy - fy;
    const int x0 = (int)fx, y0 = (int)fy, x1 = x0 + 1, y1 = y0 + 1;
    const bool vx0 = (x0 >= 0) & (x0 < 128), vx1 = (x1 >= 0) & (x1 < 128);
    const bool vy0 = (y0 >= 0) & (y0 < 128), vy1 = (y1 >= 0) & (y1 < 128);
    const int x0c = min(max(x0, 0), 127), x1c = min(max(x1, 0), 127);
    const int y0c = min(max(y0, 0), 127), y1c = min(max(y1, 0), 127);
    const float w00 = (vx0 && vy0) ? (1.f - wx) * (1.f - wy) : 0.f;
    const float w01 = (vx1 && vy0) ? wx * (1.f - wy) : 0.f;
    const float w10 = (vx0 && vy1) ? (1.f - wx) * wy : 0.f;
    const float w11 = (vx1 && vy1) ? wx * wy : 0.f;
    const long base = (long)ind[n] * 64 * 16384;
    const int a00 = y0c * 128 + x0c, a01 = y0c * 128 + x1c;
    const int a10 = y1c * 128 + x0c, a11 = y1c * 128 + x1c;
    for (int cc = 0; cc < 8; cc++) {
      const int c = og4 * 8 + cc;
      const float* f = cnn + base + (long)c * 16384;
      sx[c * 128 + p4] = f[a00] * w00 + f[a01] * w01 + f[a10] * w10 + f[a11] * w11;
    }
    if (og4 == 0) {
      sx[64 * 128 + p4] = c_it[((long)n * 128 + p4) * 2 + 0] * 4.0f;
      sx[65 * 128 + p4] = c_it[((long)n * 128 + p4) * 2 + 1] * 4.0f;
      sx[66 * 128 + p4] = cls_in[(long)n * 128 + p4];
    }
  }
  for (int idx = t; idx < 61 * 128; idx += 1024) sx[67 * 128 + idx] = 0.f;
  __syncthreads();

  float f0[16], f1[16];
#pragma unroll
  for (int r = 0; r < 16; r++) { f0[r] = 0.f; f1[r] = 0.f; }
  float* st = states + (long)ln * 131072;

  for (int l = 0; l < 8; l++) {
    const int dil = (l >= 6) ? 4 : ((l >= 4) ? 2 : 1);
    float a0[16], a1[16];
    if (gA) {
      const float* bsrc = (l == 0) ? (head_b + ow) : (res_b + (l - 1) * 128 + ow);
#pragma unroll
      for (int oo = 0; oo < 16; oo++) { a0[oo] = bsrc[oo]; a1[oo] = a0[oo]; }
    } else {
#pragma unroll
      for (int oo = 0; oo < 16; oo++) { a0[oo] = 0.f; a1[oo] = 0.f; }
    }
    const float* wp = CWS + (long)(l * 16 + wv) * 9216;   // 576 slots x 16 o
    for (int seg = 0; seg < 5; seg++) {
      const int k  = (seg < 4) ? (gA ? seg : 4 + seg) : 8;
      const int i0 = (seg < 4) ? 0 : (gA ? 0 : 64);
      const int ni = (seg < 4) ? 128 : 64;
      const int off = (k - 4) * dil;
      const int xa0 = (2 * po + off + 128) & 127;
      const int xa1 = (2 * po + 1 + off + 128) & 127;
#pragma unroll 4
      for (int s = 0; s < ni; s++) {
        const int i = i0 + s;
        const float xv0 = sx[i * 128 + xa0];
        const float xv1 = sx[i * 128 + xa1];
#pragma unroll
        for (int oo = 0; oo < 16; oo++) {
          a0[oo] = fmaf(wp[oo], xv0, a0[oo]);
          a1[oo] = fmaf(wp[oo], xv1, a1[oo]);
        }
        wp += 16;
      }
    }
    __syncthreads();           // conv reads of sx done
    if (!gA) {
#pragma unroll
      for (int oo = 0; oo < 16; oo++) {
        float2 v; v.x = a0[oo]; v.y = a1[oo];
        *(float2*)&part[(ow + oo) * 128 + 2 * po] = v;
      }
    }
    __syncthreads();
    if (gA) {
#pragma unroll
      for (int oo = 0; oo < 16; oo++) {
        const int o = ow + oo;
        const float2 pb = *(const float2*)&part[o * 128 + 2 * po];
        float v0 = fmaxf(a0[oo] + pb.x, 0.f);
        float v1 = fmaxf(a1[oo] + pb.y, 0.f);
        if (l > 0) {
          const float2 old = *(const float2*)&sx[o * 128 + 2 * po];
          v0 += old.x; v1 += old.y;
        }
        float2 nv; nv.x = v0; nv.y = v1;
        *(float2*)&sx[o * 128 + 2 * po] = nv;
        *(float2*)&st[(l * 128 + o) * 128 + 2 * po] = nv;
      }
    }
    __syncthreads();

    // ---- incremental fusion for slot l ----
    const float* fl = FWS + (long)(l * 16 + wv) * 2048;
#pragma unroll 4
    for (int i = 0; i < 128; i++) {
      const float2 xv = *(const float2*)&sx[i * 128 + 2 * po];
      const float* w = fl + i * 16;
#pragma unroll
      for (int r = 0; r < 16; r++) {
        f0[r] = fmaf(w[r], xv.x, f0[r]);
        f1[r] = fmaf(w[r], xv.y, f1[r]);
      }
    }
  }

  // ---- fusion max over positions -> graw ----
#pragma unroll
  for (int r = 0; r < 16; r++) {
    float m = fmaxf(f0[r], f1[r]);
#pragma unroll
    for (int s = 32; s > 0; s >>= 1) m = fmaxf(m, __shfl_xor(m, s, 64));
    if (po == 0) graw[(long)n * 256 + wv * 16 + r] = m;
  }
}

// =============== K_hg: hg[n][o] = bias + W1G[:,o].(graw+fus_b) ===============
__global__ __launch_bounds__(512)
void k_hg(const float* __restrict__ graw, const float* __restrict__ fus_b,
          const float* __restrict__ W1G, const float* __restrict__ p1b, const float* __restrict__ c1b,
          float* __restrict__ hg, int p0) {
  __shared__ float sg[256];
  const int n = p0 + blockIdx.x, t = threadIdx.x;
  if (t < 256) sg[t] = graw[(long)n * 256 + t] + fus_b[t];
  __syncthreads();
  float s = (t < 256) ? p1b[t] : c1b[t - 256];
  const float* w = W1G + t;
#pragma unroll 8
  for (int c = 0; c < 256; c++) s = fmaf(w[(long)c * 512], sg[c], s);
  hg[(long)n * 512 + t] = s;
}

// =============== K2: h1 GEMM (regs) + pred2/cls2 + pred3/cls3 + NMS, fused ===============
__global__ __launch_bounds__(1024) __attribute__((amdgpu_waves_per_eu(4)))
void k_h1t(const float* __restrict__ states, const float* __restrict__ W1H,
           const float* __restrict__ hg, const float* __restrict__ W2S,
           const float* __restrict__ p2b, const float* __restrict__ c2b,
           const float* __restrict__ p3w, const float* __restrict__ p3b,
           const float* __restrict__ c3w, const float* __restrict__ c3b,
           const float* __restrict__ i_it, float* __restrict__ out, int p0) {
  __shared__ float xb[2][2048];   // states staging, 16 rows x 128 pos dbuf (16 KB)
  __shared__ float hx[16384];     // h1 chunk / h2 buffer (64 KB)
  const int ln = blockIdx.x, n = p0 + ln, t = threadIdx.x;
  const int po = t & 63;
  const int wv = __builtin_amdgcn_readfirstlane(t >> 6);
  const float* xs = states + (long)ln * 131072;

  // ---- phase 1: h1 = relu(W1H @ states + hg); wave wv owns 32 h1 rows ----
  float h0[32], h1v[32];
#pragma unroll
  for (int r = 0; r < 32; r++) { h0[r] = 0.f; h1v[r] = 0.f; }
  const float* wbase = W1H + (long)wv * 32768;
  float2 px = ((const float2*)xs)[t];
  int buf = 0;
  for (int c = 0; c < 64; c++) {
    ((float2*)xb[buf])[t] = px;
    __syncthreads();
    if (c + 1 < 64) px = ((const float2*)(xs + (long)(c + 1) * 2048))[t];
    const float* wc = wbase + c * 512;
#pragma unroll 4
    for (int i = 0; i < 16; i++) {
      const float2 xv = *(const float2*)&xb[buf][i * 128 + 2 * po];
      const float* w = wc + i * 32;          // wave-uniform -> s_load
#pragma unroll
      for (int r = 0; r < 32; r++) {
        h0[r] = fmaf(w[r], xv.x, h0[r]);
        h1v[r] = fmaf(w[r], xv.y, h1v[r]);
      }
    }
    __syncthreads();
    buf ^= 1;
  }
  {
    const float* hgp = hg + (long)n * 512 + wv * 32;
#pragma unroll
    for (int r = 0; r < 32; r++) {
      h0[r] = fmaxf(h0[r] + hgp[r], 0.f);
      h1v[r] = fmaxf(h1v[r] + hgp[r], 0.f);
    }
  }

  // ---- phase 2: pred2/cls2 over 4 chunks of 128 h1 rows ----
  float ap0[4], ap1[4], ac0[4], ac1[4];
#pragma unroll
  for (int jj = 0; jj < 4; jj++) { ap0[jj] = 0.f; ap1[jj] = 0.f; ac0[jj] = 0.f; ac1[jj] = 0.f; }
#pragma unroll
  for (int c = 0; c < 4; c++) {
    __syncthreads();
    if ((wv >> 2) == c) {
#pragma unroll
      for (int r = 0; r < 32; r++) {
        float2 v; v.x = h0[r]; v.y = h1v[r];
        *(float2*)&hx[((wv & 3) * 32 + r) * 128 + 2 * po] = v;
      }
    }
    __syncthreads();
    const float* w2 = W2S + (long)(c * 16 + wv) * 512;
#pragma unroll 4
    for (int i = 0; i < 128; i++) {
      const float2 xv = *(const float2*)&hx[i * 128 + 2 * po];
      const float* w = w2 + i * 4;
      if (c < 2) {
#pragma unroll
        for (int jj = 0; jj < 4; jj++) {
          ap0[jj] = fmaf(w[jj], xv.x, ap0[jj]);
          ap1[jj] = fmaf(w[jj], xv.y, ap1[jj]);
        }
      } else {
#pragma unroll
        for (int jj = 0; jj < 4; jj++) {
          ac0[jj] = fmaf(w[jj], xv.x, ac0[jj]);
          ac1[jj] = fmaf(w[jj], xv.y, ac1[jj]);
        }
      }
    }
  }
  __syncthreads();
  // h2 rows: j<64 pred2, j>=64 cls2 (into hx)
#pragma unroll
  for (int jj = 0; jj < 4; jj++) {
    const int j = wv * 4 + jj;
    float2 vp; vp.x = fmaxf(ap0[jj] + p2b[j], 0.f); vp.y = fmaxf(ap1[jj] + p2b[j], 0.f);
    *(float2*)&hx[j * 128 + 2 * po] = vp;
    float2 vc; vc.x = fmaxf(ac0[jj] + c2b[j], 0.f); vc.y = fmaxf(ac1[jj] + c2b[j], 0.f);
    *(float2*)&hx[(64 + j) * 128 + 2 * po] = vc;
  }
  __syncthreads();

  // ---- phase 3: pred3/cls3 + outputs + NMS ----
  float sig = 0.f;
  const int pp = t & 127;
  if (t < 128) {
    float o0v = p3b[0], o1v = p3b[1], cv = c3b[0];
    for (int j = 0; j < 64; j++) {
      const float hp = hx[j * 128 + pp];
      const float hc = hx[(64 + j) * 128 + pp];
      o0v = fmaf(p3w[j], hp, o0v);
      o1v = fmaf(p3w[64 + j], hp, o1v);
      cv = fmaf(c3w[j], hc, cv);
    }
    const long ip = ((long)n * 128 + pp) * 2;
    out[ip + 0] = i_it[ip + 0] * 4.f + o0v;
    out[ip + 1] = i_it[ip + 1] * 4.f + o1v;
    out[131072 + (long)n * 128 + pp] = cv;
    sig = 1.f / (1.f + expf(-cv));
  }
  __syncthreads();
  if (t < 128) xb[0][pp] = sig;
  __syncthreads();
  if (t < 128) {
    float m = xb[0][pp];
#pragma unroll
    for (int s = 1; s <= 2; s++) {
      m = fmaxf(m, xb[0][(pp + s) & 127]);
      m = fmaxf(m, xb[0][(pp + 128 - s) & 127]);
    }
    out[196608 + (long)n * 128 + pp] = (sig >= m) ? sig : 0.f;
  }
}

extern "C" void kernel_launch(void* const* d_in, const int* in_sizes, int n_in,
                              void* d_out, int out_size, void* d_ws, size_t ws_size,
                              hipStream_t stream) {
  const float* cnn      = (const float*)d_in[0];
  const float* i_it     = (const float*)d_in[1];
  const float* c_it     = (const float*)d_in[2];
  const float* it_cls   = (const float*)d_in[3];
  const int*   ind      = (const int*)d_in[4];
  const float* head_w   = (const float*)d_in[5];
  const float* head_b   = (const float*)d_in[6];
  const float* res_w    = (const float*)d_in[7];
  const float* res_b    = (const float*)d_in[8];
  const float* fusion_w = (const float*)d_in[9];
  const float* fusion_b = (const float*)d_in[10];
  const float* pred1_w  = (const float*)d_in[11];
  const float* pred1_b  = (const float*)d_in[12];
  const float* pred2_w  = (const float*)d_in[13];
  const float* pred2_b  = (const float*)d_in[14];
  const float* pred3_w  = (const float*)d_in[15];
  const float* pred3_b  = (const float*)d_in[16];
  const float* cls1_w   = (const float*)d_in[17];
  const float* cls1_b   = (const float*)d_in[18];
  const float* cls2_w   = (const float*)d_in[19];
  const float* cls2_b   = (const float*)d_in[20];
  const float* cls3_w   = (const float*)d_in[21];
  const float* cls3_b   = (const float*)d_in[22];
  float* ws = (float*)d_ws;
  float* out = (float*)d_out;

  k_repack<<<(int)((REPACK_N + 255) / 256), 256, 0, stream>>>(
      head_w, res_w, fusion_w, pred1_w, cls1_w, pred2_w, cls2_w, ws);

  // chunk polygons by workspace (states only: 131072 floats/poly); balanced rounds
  long avail_f = (long)(ws_size / 4) - OFF_DYN;
  long Cl = avail_f / 131072;
  int C = (Cl >= 512) ? 512 : ((Cl >= 256) ? 256 : (int)(Cl < 1 ? 1 : Cl));
  float* states = ws + OFF_DYN;

  for (int p0 = 0; p0 < 512; p0 += C) {
    int Cc = (512 - p0 < C) ? (512 - p0) : C;
    k_conv<<<Cc, 1024, 0, stream>>>(cnn, i_it, c_it, it_cls, ind,
                                    ws + OFF_CWS, ws + OFF_FWS, head_b, res_b,
                                    ws + OFF_GRAW, states, p0);
    k_hg<<<Cc, 512, 0, stream>>>(ws + OFF_GRAW, fusion_b, ws + OFF_W1G,
                                 pred1_b, cls1_b, ws + OFF_HG, p0);
    k_h1t<<<Cc, 1024, 0, stream>>>(states, ws + OFF_W1H, ws + OFF_HG, ws + OFF_W2S,
                                   pred2_b, cls2_b, pred3_w, pred3_b, cls3_w, cls3_b,
                                   i_it, out, p0);
  }
}